// Round 10
// baseline (285.638 us; speedup 1.0000x reference)
//
#include <hip/hip_runtime.h>
#include <math.h>

#define NEGF (-1.0e9f)
#define NB 4   // batches per block

typedef __attribute__((ext_vector_type(8))) short short8;
typedef __attribute__((ext_vector_type(4))) float f32x4;

// release/acquire barrier WITHOUT the vmcnt(0) drain __syncthreads() forces:
// LDS ops are ordered by lgkmcnt(0); global prefetch stays in flight (T4).
#define LGKM_BAR()                                         \
    do {                                                   \
        asm volatile("s_waitcnt lgkmcnt(0)" ::: "memory"); \
        __builtin_amdgcn_s_barrier();                      \
    } while (0)

static __device__ __forceinline__ unsigned short bf16_rne(float f) {
    unsigned int u = __float_as_uint(f);
    u += 0x7FFFu + ((u >> 16) & 1u);
    return (unsigned short)(u >> 16);
}

// packed 2x f32 -> 2x bf16 (RNE), D[15:0]=cvt(S0), D[31:16]=cvt(S1)
static __device__ __forceinline__ unsigned cvt_pk_bf16(float a, float b) {
    unsigned r;
    asm("v_cvt_pk_bf16_f32 %0, %1, %2" : "=v"(r) : "v"(a), "v"(b));
    return r;
}

// Kernel A: segment boundaries from sorted batch_index.
__global__ void seg_bounds_kernel(const int* __restrict__ bi, int M, int B,
                                  int* __restrict__ seg) {
    int m = blockIdx.x * blockDim.x + threadIdx.x;
    if (m >= M) return;
    int cur = bi[m];
    if (m == 0) {
        for (int b = 0; b <= cur; ++b) seg[b] = 0;
    } else {
        int prev = bi[m - 1];
        for (int b = prev + 1; b <= cur; ++b) seg[b] = m;
    }
    if (m == M - 1) {
        for (int b = cur + 1; b <= B; ++b) seg[b] = M;
    }
}

// Kernel P: split w2 [64 k][128 col] into hi/lo bf16 in per-lane MFMA
// B-fragment order. ushort layout: [cg 8][ks 2][p 2][slot 64][e 8],
// slot = kg*16+lane16, value = bf16split_p(w2[ks*32+kg*8+e][cg*16+lane16]).
__global__ void prep_w2_kernel(const float* __restrict__ w2,
                               unsigned short* __restrict__ wf) {
    int t = blockIdx.x * blockDim.x + threadIdx.x;   // 0..8191
    if (t >= 8192) return;
    int e = t & 7, slot = (t >> 3) & 63, ks = (t >> 9) & 1, cg = t >> 10;
    int lane16 = slot & 15, kg = slot >> 4;
    int k = ks * 32 + kg * 8 + e;
    int col = cg * 16 + lane16;
    float w = w2[k * 128 + col];
    unsigned ub = __float_as_uint(w);
    unsigned short hi = (unsigned short)(ub >> 16);               // trunc
    float lof = w - __uint_as_float(ub & 0xFFFF0000u);
    unsigned short lo = bf16_rne(lof);
    wf[((cg * 2 + ks) * 2 + 0) * 512 + slot * 8 + e] = hi;
    wf[((cg * 2 + ks) * 2 + 1) * 512 + slot * 8 + e] = lo;
}

// 128-thread (2-wave) block, NB consecutive batches.
// R9 post-mortem: ~80% of wave-time was stall. Fixes this round:
//  (1) tile-loop barriers are raw s_barrier + lgkmcnt(0) only — no vmcnt
//      drain, so cold-HBM muon prefetch stays in flight across barriers;
//  (2) 2-deep prefetch ping-pong (static bufA/bufB, manual 2x unroll):
//      tile t+2 issued at top of iter t, consumed end of iter t+1;
//  (3) wpk stored PERMUTED (idx=(k&15)*4+(k>>4)) so quad lanes read 4
//      distinct banks (R9's [64][4] put ko={0,16,32,48} all on bank 0:
//      +0.77e7 conflict cycles).
__global__ __launch_bounds__(128, 3) void critic_kernel(
    const float* __restrict__ muons,   // [M,3]
    const float* __restrict__ conds,   // [B,4]
    const int*   __restrict__ seg,     // [B+1]
    const float* __restrict__ w1,      // [7,64]
    const float* __restrict__ b1,      // [64]
    const unsigned short* __restrict__ w2frag,  // packed by prep_w2_kernel
    const float* __restrict__ b2,      // [128]
    const float* __restrict__ w3,      // [132,128]
    const float* __restrict__ b3,      // [128]
    const float* __restrict__ w4,      // [128]
    const float* __restrict__ b4,      // [1]
    float* __restrict__ out,           // [B]
    float scale, int Btot)
{
    __shared__ __align__(16) char  alds[2][4096]; // [p][row 32][k 64] bf16, swizzled
    __shared__ __align__(16) float wpk[64][4];    // permuted: [(k&15)*4+(k>>4)]
    __shared__ float din[132];
    __shared__ float red[2];

    const int tid  = threadIdx.x;
    const int wave = tid >> 6;
    const int lane = tid & 63;
    const int l16  = lane & 15;
    const int lkg  = lane >> 4;

    // ---- this wave's 4 col-groups of w2 hi/lo: 16 x dwordx4 = 64 VGPR ----
    short8 bhi[4][2], blo[4][2];
    {
        const short8* wf = (const short8*)w2frag;
        #pragma unroll
        for (int c = 0; c < 4; ++c) {
            const int cg = wave * 4 + c;
            #pragma unroll
            for (int ks = 0; ks < 2; ++ks) {
                bhi[c][ks] = wf[((cg * 2 + ks) * 2 + 0) * 64 + lane];
                blo[c][ks] = wf[((cg * 2 + ks) * 2 + 1) * 64 + lane];
            }
        }
    }

    // ---- phase-A geometry: 4 threads/muon, 16 k-outputs each ----
    const int arow = wave * 16 + (lane >> 2);   // muon row in tile, 0..31
    const int kq   = lane & 3;                  // k-quad: k-offset kq*16
    const unsigned aswz  = (unsigned)((arow & 7) << 4);
    const unsigned wadr0 = ((unsigned)(arow * 128 + kq * 32)) ^ aswz;
    const unsigned wadr1 = ((unsigned)(arow * 128 + kq * 32 + 16)) ^ aswz;

    // ---- phase-B read addresses ----
    unsigned rb[2];
    #pragma unroll
    for (int rt = 0; rt < 2; ++rt) {
        const int row = rt * 16 + l16;
        rb[rt] = ((unsigned)(row * 128 + lkg * 16)) ^ ((unsigned)((row & 7) << 4));
    }

    // L1 for one muon -> split hi/lo -> swizzled LDS write (16 outputs)
    auto l1_write = [&](float x0, float x1, float x2) {
        float hv[16];
        #pragma unroll
        for (int i = 0; i < 16; ++i) {
            // permuted wpk: row i*4+kq holds k = kq*16 + i  (conflict-free)
            const f32x4 wr = *(const f32x4*)&wpk[i * 4 + kq][0];
            float s = wr[3];
            s = fmaf(x0, wr[0], s);
            s = fmaf(x1, wr[1], s);
            s = fmaf(x2, wr[2], s);
            hv[i] = fmaxf(s, 0.2f * s);
        }
        unsigned hw[8], lw[8];
        #pragma unroll
        for (int j = 0; j < 8; ++j) {
            const unsigned h = cvt_pk_bf16(hv[2 * j], hv[2 * j + 1]);
            hw[j] = h;
            lw[j] = cvt_pk_bf16(hv[2 * j]     - __uint_as_float(h << 16),
                                hv[2 * j + 1] - __uint_as_float(h & 0xFFFF0000u));
        }
        *(uint4*)(&alds[0][wadr0]) = make_uint4(hw[0], hw[1], hw[2], hw[3]);
        *(uint4*)(&alds[0][wadr1]) = make_uint4(hw[4], hw[5], hw[6], hw[7]);
        *(uint4*)(&alds[1][wadr0]) = make_uint4(lw[0], lw[1], lw[2], lw[3]);
        *(uint4*)(&alds[1][wadr1]) = make_uint4(lw[4], lw[5], lw[6], lw[7]);
    };

// One tile iteration: drainless bar -> issue loads(t+2) into I* ->
// MFMA+fold(t) -> drainless bar -> l1_write(C* = muons of tile t+1).
#define TILE_ITER(TCUR, I0, I1, I2, C0, C1, C2)                             \
    {                                                                       \
        const int _t = (TCUR);                                              \
        LGKM_BAR(); /* A(_t) visible to both waves */                       \
        I0 = 0.f; I1 = 0.f; I2 = 0.f;                                       \
        {                                                                   \
            const int _rem2 = nrows - (_t + 2) * 32;                        \
            if (_rem2 > 0 && arow < _rem2) {                                \
                const int _gm = start + (_t + 2) * 32 + arow;               \
                I0 = muons[_gm * 3 + 0];                                    \
                I1 = muons[_gm * 3 + 1];                                    \
                I2 = muons[_gm * 3 + 2];                                    \
            }                                                               \
        }                                                                   \
        const int _cnt = min(32, nrows - _t * 32);                          \
        _Pragma("unroll")                                                   \
        for (int rt = 0; rt < 2; ++rt) {                                    \
            const short8 ah0 = *(const short8*)(&alds[0][rb[rt]]);          \
            const short8 ah1 = *(const short8*)(&alds[0][rb[rt] ^ 64u]);    \
            const short8 al0 = *(const short8*)(&alds[1][rb[rt]]);          \
            const short8 al1 = *(const short8*)(&alds[1][rb[rt] ^ 64u]);    \
            f32x4 acc[4];                                                   \
            __builtin_amdgcn_s_setprio(1);                                  \
            _Pragma("unroll")                                               \
            for (int c = 0; c < 4; ++c) {                                   \
                f32x4 a = (f32x4){0.f, 0.f, 0.f, 0.f};                      \
                a = __builtin_amdgcn_mfma_f32_16x16x32_bf16(ah0, bhi[c][0], a, 0, 0, 0); \
                a = __builtin_amdgcn_mfma_f32_16x16x32_bf16(ah1, bhi[c][1], a, 0, 0, 0); \
                a = __builtin_amdgcn_mfma_f32_16x16x32_bf16(al0, bhi[c][0], a, 0, 0, 0); \
                a = __builtin_amdgcn_mfma_f32_16x16x32_bf16(al1, bhi[c][1], a, 0, 0, 0); \
                a = __builtin_amdgcn_mfma_f32_16x16x32_bf16(ah0, blo[c][0], a, 0, 0, 0); \
                a = __builtin_amdgcn_mfma_f32_16x16x32_bf16(ah1, blo[c][1], a, 0, 0, 0); \
                acc[c] = a;                                                 \
            }                                                               \
            __builtin_amdgcn_s_setprio(0);                                  \
            _Pragma("unroll")                                               \
            for (int c = 0; c < 4; ++c)                                     \
                _Pragma("unroll")                                           \
                for (int j = 0; j < 4; ++j) {                               \
                    const int r = rt * 16 + lkg * 4 + j;                    \
                    gmax[c] = fmaxf(gmax[c], (r < _cnt) ? acc[c][j] : NEGF);\
                }                                                           \
        }                                                                   \
        LGKM_BAR(); /* reads done; safe to overwrite A */                   \
        {                                                                   \
            const int _rem1 = nrows - (_t + 1) * 32;                        \
            if (_rem1 > 0 && arow < _rem1) l1_write(C0, C1, C2);            \
        }                                                                   \
    }

    for (int bi = 0; bi < NB; ++bi) {
        const int b = blockIdx.x * NB + bi;
        if (b >= Btot) break;

        const float c0 = conds[b * 4 + 0];
        const float c1 = conds[b * 4 + 1];
        const float c2 = conds[b * 4 + 2];
        const float c3 = conds[b * 4 + 3];
        const int start = seg[b];
        const int end   = seg[b + 1];
        const int nrows = end - start;

        // ---- per-batch packed L1 weights (PERMUTED store) ----
        if (tid < 64) {
            float e = b1[tid];
            e = fmaf(c0, w1[3 * 64 + tid], e);
            e = fmaf(c1, w1[4 * 64 + tid], e);
            e = fmaf(c2, w1[5 * 64 + tid], e);
            e = fmaf(c3, w1[6 * 64 + tid], e);
            const int p = (tid & 15) * 4 + (tid >> 4);
            wpk[p][0] = w1[0 * 64 + tid];
            wpk[p][1] = w1[1 * 64 + tid];
            wpk[p][2] = w1[2 * 64 + tid];
            wpk[p][3] = e;
        }
        __syncthreads();   // wpk ready (cold path, full drain OK)

        float gmax[4];
        #pragma unroll
        for (int c = 0; c < 4; ++c) gmax[c] = NEGF;

        if (nrows > 0) {
            const int ntiles = (nrows + 31) >> 5;

            // prologue: tile0 load+write; issue tile1 into bufB
            float bA0, bA1, bA2, bB0, bB1, bB2;
            {
                float p0 = 0.f, p1 = 0.f, p2 = 0.f;
                const bool pv = arow < nrows;
                if (pv) {
                    const int gm = start + arow;
                    p0 = muons[gm * 3 + 0];
                    p1 = muons[gm * 3 + 1];
                    p2 = muons[gm * 3 + 2];
                }
                bB0 = 0.f; bB1 = 0.f; bB2 = 0.f;
                const int rem1 = nrows - 32;
                if (rem1 > 0 && arow < rem1) {
                    const int gm = start + 32 + arow;
                    bB0 = muons[gm * 3 + 0];
                    bB1 = muons[gm * 3 + 1];
                    bB2 = muons[gm * 3 + 2];
                }
                if (pv) l1_write(p0, p1, p2);
            }

            int t = 0;
            for (; t + 1 < ntiles; t += 2) {
                TILE_ITER(t,     bA0, bA1, bA2, bB0, bB1, bB2);
                TILE_ITER(t + 1, bB0, bB1, bB2, bA0, bA1, bA2);
            }
            if (t < ntiles)
                TILE_ITER(t, bA0, bA1, bA2, bB0, bB1, bB2);
        }

        // ---- din: wave-local columns (wave w owns cols w*64..+63) ----
        #pragma unroll
        for (int c = 0; c < 4; ++c) {
            float v = gmax[c];
            v = fmaxf(v, __shfl_xor(v, 16, 64));
            v = fmaxf(v, __shfl_xor(v, 32, 64));
            if (lane < 16) {
                const int col = wave * 64 + c * 16 + lane;
                const float biased = v + b2[col];
                const float actv = fmaxf(biased, 0.2f * biased);  // deferred leaky
                din[col] = (nrows > 0) ? actv : NEGF;             // empty-seg guard
            }
        }
        if (tid < 4) din[128 + tid] = conds[b * 4 + tid];
        LGKM_BAR();   // din complete

        // ---- decision net: one output column per thread, 4-way ILP ----
        float g0 = b3[tid], g1 = 0.f, g2 = 0.f, g3 = 0.f;
        #pragma unroll 4
        for (int i = 0; i < 132; i += 4) {
            g0 = fmaf(din[i + 0], w3[(i + 0) * 128 + tid], g0);
            g1 = fmaf(din[i + 1], w3[(i + 1) * 128 + tid], g1);
            g2 = fmaf(din[i + 2], w3[(i + 2) * 128 + tid], g2);
            g3 = fmaf(din[i + 3], w3[(i + 3) * 128 + tid], g3);
        }
        float g = (g0 + g1) + (g2 + g3);
        g = fmaxf(g, 0.2f * g);
        float part = g * w4[tid];
        #pragma unroll
        for (int s = 1; s < 64; s <<= 1)
            part += __shfl_xor(part, s, 64);
        if (lane == 0) red[wave] = part;
        LGKM_BAR();
        if (tid == 0) {
            float sc = (red[0] + red[1] + b4[0]) * scale;
            out[b] = fminf(fmaxf(sc, -1000.0f), 1000.0f);
        }
        __syncthreads();   // red/din stable before next batch reuses them
    }
#undef TILE_ITER
}

extern "C" void kernel_launch(void* const* d_in, const int* in_sizes, int n_in,
                              void* d_out, int out_size, void* d_ws, size_t ws_size,
                              hipStream_t stream) {
    const float* muons = (const float*)d_in[0];
    const int*   bidx  = (const int*)d_in[1];
    const float* conds = (const float*)d_in[2];
    // d_in[3] = batch_size scalar (derive B from conditions instead)
    const float* w1 = (const float*)d_in[4];
    const float* b1 = (const float*)d_in[5];
    const float* w2 = (const float*)d_in[6];
    const float* b2 = (const float*)d_in[7];
    const float* w3 = (const float*)d_in[8];
    const float* b3 = (const float*)d_in[9];
    const float* w4 = (const float*)d_in[10];
    const float* b4 = (const float*)d_in[11];

    const int M = in_sizes[0] / 3;
    const int B = in_sizes[2] / 4;
    int* seg = (int*)d_ws;                                   // (B+1) ints
    const size_t off = (((size_t)(B + 1)) * 4 + 255) & ~(size_t)255;
    unsigned short* w2frag = (unsigned short*)((char*)d_ws + off);  // 32 KB
    const float scale = 1.0f / fmaxf(1.0f, sqrtf((float)B));

    seg_bounds_kernel<<<(M + 255) / 256, 256, 0, stream>>>(bidx, M, B, seg);
    prep_w2_kernel<<<32, 256, 0, stream>>>(w2, w2frag);
    const int nblk = (B + NB - 1) / NB;
    critic_kernel<<<nblk, 128, 0, stream>>>(muons, conds, seg,
                                            w1, b1, w2frag, b2, w3, b3, w4, b4,
                                            (float*)d_out, scale, B);
}

// Round 12
// 278.607 us; speedup vs baseline: 1.0252x; 1.0252x over previous
//
#include <hip/hip_runtime.h>
#include <math.h>

#define NEGF (-1.0e9f)
#define NB 8   // batches per block; grid 2048 = 8 blocks/CU

typedef __attribute__((ext_vector_type(8))) short short8;
typedef __attribute__((ext_vector_type(4))) float f32x4;

static __device__ __forceinline__ unsigned short bf16_rne(float f) {
    unsigned int u = __float_as_uint(f);
    u += 0x7FFFu + ((u >> 16) & 1u);
    return (unsigned short)(u >> 16);
}

// packed 2x f32 -> 2x bf16 (RNE), D[15:0]=cvt(S0), D[31:16]=cvt(S1)
static __device__ __forceinline__ unsigned cvt_pk_bf16(float a, float b) {
    unsigned r;
    asm("v_cvt_pk_bf16_f32 %0, %1, %2" : "=v"(r) : "v"(a), "v"(b));
    return r;
}

// Kernel A: segment boundaries from sorted batch_index.
__global__ void seg_bounds_kernel(const int* __restrict__ bi, int M, int B,
                                  int* __restrict__ seg) {
    int m = blockIdx.x * blockDim.x + threadIdx.x;
    if (m >= M) return;
    int cur = bi[m];
    if (m == 0) {
        for (int b = 0; b <= cur; ++b) seg[b] = 0;
    } else {
        int prev = bi[m - 1];
        for (int b = prev + 1; b <= cur; ++b) seg[b] = m;
    }
    if (m == M - 1) {
        for (int b = cur + 1; b <= B; ++b) seg[b] = M;
    }
}

// Kernel P: split w2 [64 k][128 col] into hi/lo bf16 in per-lane MFMA
// B-fragment order. ushort layout: [cg 8][ks 2][p 2][slot 64][e 8],
// slot = kg*16+lane16, value = bf16split_p(w2[ks*32+kg*8+e][cg*16+lane16]).
__global__ void prep_w2_kernel(const float* __restrict__ w2,
                               unsigned short* __restrict__ wf) {
    int t = blockIdx.x * blockDim.x + threadIdx.x;   // 0..8191
    if (t >= 8192) return;
    int e = t & 7, slot = (t >> 3) & 63, ks = (t >> 9) & 1, cg = t >> 10;
    int lane16 = slot & 15, kg = slot >> 4;
    int k = ks * 32 + kg * 8 + e;
    int col = cg * 16 + lane16;
    float w = w2[k * 128 + col];
    unsigned ub = __float_as_uint(w);
    unsigned short hi = (unsigned short)(ub >> 16);               // trunc
    float lof = w - __uint_as_float(ub & 0xFFFF0000u);
    unsigned short lo = bf16_rne(lof);
    wf[((cg * 2 + ks) * 2 + 0) * 512 + slot * 8 + e] = hi;
    wf[((cg * 2 + ks) * 2 + 1) * 512 + slot * 8 + e] = lo;
}

// 128-thread (2-wave) block, NB consecutive batches.
// R11 post-mortem: `wa + 16` on an already-XOR-swizzled base carried into
// bit 5 when aswz set bit 4 (and overflowed plane 0 at the extreme) ->
// corrupted fragments, absmax 1000. Correct second-half address is
// `wa ^ 16` (pre-XOR +16 == bit-4 flip since kq*32 is 32-aligned).
// Structure (unchanged from R11's intent): 64-row tiles halve barrier
// frequency vs R10 and give ~1.9k-cyc MFMA clusters to hide the 1-deep
// muon prefetch; NB=8 -> grid 2048 = 8 blocks/CU = 4 waves/SIMD.
__global__ __launch_bounds__(128, 3) void critic_kernel(
    const float* __restrict__ muons,   // [M,3]
    const float* __restrict__ conds,   // [B,4]
    const int*   __restrict__ seg,     // [B+1]
    const float* __restrict__ w1,      // [7,64]
    const float* __restrict__ b1,      // [64]
    const unsigned short* __restrict__ w2frag,  // packed by prep_w2_kernel
    const float* __restrict__ b2,      // [128]
    const float* __restrict__ w3,      // [132,128]
    const float* __restrict__ b3,      // [128]
    const float* __restrict__ w4,      // [128]
    const float* __restrict__ b4,      // [1]
    float* __restrict__ out,           // [B]
    float scale, int Btot)
{
    __shared__ __align__(16) char  alds[2][8192]; // [p][row 64][k 64] bf16, swizzled
    __shared__ __align__(16) float wpk[64][4];    // permuted: [(k&15)*4+(k>>4)]
    __shared__ float din[132];
    __shared__ float red[2];

    const int tid  = threadIdx.x;
    const int wave = tid >> 6;
    const int lane = tid & 63;
    const int l16  = lane & 15;
    const int lkg  = lane >> 4;

    // ---- this wave's 4 col-groups of w2 hi/lo: 16 x dwordx4 = 64 VGPR ----
    short8 bhi[4][2], blo[4][2];
    {
        const short8* wf = (const short8*)w2frag;
        #pragma unroll
        for (int c = 0; c < 4; ++c) {
            const int cg = wave * 4 + c;
            #pragma unroll
            for (int ks = 0; ks < 2; ++ks) {
                bhi[c][ks] = wf[((cg * 2 + ks) * 2 + 0) * 64 + lane];
                blo[c][ks] = wf[((cg * 2 + ks) * 2 + 1) * 64 + lane];
            }
        }
    }

    // ---- phase-A geometry: 4 threads/muon, 16 k-outputs, 2 muons/thread ----
    const int arow = wave * 16 + (lane >> 2);   // first muon row, 0..31 (2nd: +32)
    const int kq   = lane & 3;                  // k-quad: k-offset kq*16
    const unsigned aswz  = (unsigned)((arow & 7) << 4);
    const unsigned wadr0 = ((unsigned)(arow * 128 + kq * 32)) ^ aswz;  // row arow
    // second muon: row arow+32 -> same swizzle ((row&7) unchanged), +4096 B

    // ---- phase-B read addresses (4 row-tiles of 16) ----
    unsigned rbA[4];
    #pragma unroll
    for (int rt = 0; rt < 4; ++rt) {
        const int row = rt * 16 + l16;
        rbA[rt] = ((unsigned)(row * 128 + lkg * 16)) ^ ((unsigned)((row & 7) << 4));
    }

    // L1 for one muon -> split hi/lo -> swizzled LDS write (16 outputs)
    auto l1_write = [&](float x0, float x1, float x2, unsigned wa) {
        float hv[16];
        #pragma unroll
        for (int i = 0; i < 16; ++i) {
            // permuted wpk: row i*4+kq holds k = kq*16 + i  (conflict-free)
            const f32x4 wr = *(const f32x4*)&wpk[i * 4 + kq][0];
            float s = wr[3];
            s = fmaf(x0, wr[0], s);
            s = fmaf(x1, wr[1], s);
            s = fmaf(x2, wr[2], s);
            hv[i] = fmaxf(s, 0.2f * s);
        }
        unsigned hw[8], lw[8];
        #pragma unroll
        for (int j = 0; j < 8; ++j) {
            const unsigned h = cvt_pk_bf16(hv[2 * j], hv[2 * j + 1]);
            hw[j] = h;
            lw[j] = cvt_pk_bf16(hv[2 * j]     - __uint_as_float(h << 16),
                                hv[2 * j + 1] - __uint_as_float(h & 0xFFFF0000u));
        }
        // second 16B half: bit-4 flip via XOR (NOT +16: wa is post-swizzle)
        *(uint4*)(&alds[0][wa])        = make_uint4(hw[0], hw[1], hw[2], hw[3]);
        *(uint4*)(&alds[0][wa ^ 16u])  = make_uint4(hw[4], hw[5], hw[6], hw[7]);
        *(uint4*)(&alds[1][wa])        = make_uint4(lw[0], lw[1], lw[2], lw[3]);
        *(uint4*)(&alds[1][wa ^ 16u])  = make_uint4(lw[4], lw[5], lw[6], lw[7]);
    };

    for (int bi = 0; bi < NB; ++bi) {
        const int b = blockIdx.x * NB + bi;
        if (b >= Btot) break;

        const float c0 = conds[b * 4 + 0];
        const float c1 = conds[b * 4 + 1];
        const float c2 = conds[b * 4 + 2];
        const float c3 = conds[b * 4 + 3];
        const int start = seg[b];
        const int end   = seg[b + 1];
        const int nrows = end - start;

        // ---- per-batch packed L1 weights (PERMUTED store) ----
        if (tid < 64) {
            float e = b1[tid];
            e = fmaf(c0, w1[3 * 64 + tid], e);
            e = fmaf(c1, w1[4 * 64 + tid], e);
            e = fmaf(c2, w1[5 * 64 + tid], e);
            e = fmaf(c3, w1[6 * 64 + tid], e);
            const int p = (tid & 15) * 4 + (tid >> 4);
            wpk[p][0] = w1[0 * 64 + tid];
            wpk[p][1] = w1[1 * 64 + tid];
            wpk[p][2] = w1[2 * 64 + tid];
            wpk[p][3] = e;
        }
        __syncthreads();   // wpk ready; also fences prev batch's din/red reads

        float gmax[4];
        #pragma unroll
        for (int c = 0; c < 4; ++c) gmax[c] = NEGF;

        if (nrows > 0) {
            const int ntiles = (nrows + 63) >> 6;   // 64-row tiles

            // prologue: tile 0 -> LDS (unhidden, once per batch)
            {
                if (arow < nrows) {
                    const int gm = start + arow;
                    l1_write(muons[gm * 3 + 0], muons[gm * 3 + 1],
                             muons[gm * 3 + 2], wadr0);
                }
                if (arow + 32 < nrows) {
                    const int gm = start + arow + 32;
                    l1_write(muons[gm * 3 + 0], muons[gm * 3 + 1],
                             muons[gm * 3 + 2], wadr0 + 4096u);
                }
            }

            for (int t = 0; t < ntiles; ++t) {
                const int rem = nrows - t * 64;
                const int cnt = min(64, rem);
                __syncthreads();   // A(t) visible to both waves

                // 1-deep prefetch of tile t+1 muons (lands under ~1.9k cyc MFMA)
                const int rem1 = rem - 64;
                float pA0 = 0.f, pA1 = 0.f, pA2 = 0.f;
                float pB0 = 0.f, pB1 = 0.f, pB2 = 0.f;
                const bool vA = arow < rem1;
                const bool vB = arow + 32 < rem1;
                if (vA) {
                    const int gm = start + (t + 1) * 64 + arow;
                    pA0 = muons[gm * 3 + 0];
                    pA1 = muons[gm * 3 + 1];
                    pA2 = muons[gm * 3 + 2];
                }
                if (vB) {
                    const int gm = start + (t + 1) * 64 + arow + 32;
                    pB0 = muons[gm * 3 + 0];
                    pB1 = muons[gm * 3 + 1];
                    pB2 = muons[gm * 3 + 2];
                }

                // phase B: 4 row-tiles x (read A-frags, 24 MFMA, fold)
                #pragma unroll
                for (int rt = 0; rt < 4; ++rt) {
                    const short8 ah0 = *(const short8*)(&alds[0][rbA[rt]]);
                    const short8 ah1 = *(const short8*)(&alds[0][rbA[rt] ^ 64u]);
                    const short8 al0 = *(const short8*)(&alds[1][rbA[rt]]);
                    const short8 al1 = *(const short8*)(&alds[1][rbA[rt] ^ 64u]);

                    f32x4 acc[4];
                    __builtin_amdgcn_s_setprio(1);
                    #pragma unroll
                    for (int c = 0; c < 4; ++c) {
                        f32x4 a = (f32x4){0.f, 0.f, 0.f, 0.f};
                        a = __builtin_amdgcn_mfma_f32_16x16x32_bf16(ah0, bhi[c][0], a, 0, 0, 0);
                        a = __builtin_amdgcn_mfma_f32_16x16x32_bf16(ah1, bhi[c][1], a, 0, 0, 0);
                        a = __builtin_amdgcn_mfma_f32_16x16x32_bf16(al0, bhi[c][0], a, 0, 0, 0);
                        a = __builtin_amdgcn_mfma_f32_16x16x32_bf16(al1, bhi[c][1], a, 0, 0, 0);
                        a = __builtin_amdgcn_mfma_f32_16x16x32_bf16(ah0, blo[c][0], a, 0, 0, 0);
                        a = __builtin_amdgcn_mfma_f32_16x16x32_bf16(ah1, blo[c][1], a, 0, 0, 0);
                        acc[c] = a;
                    }
                    __builtin_amdgcn_s_setprio(0);

                    if (cnt == 64) {           // fast path: no masking
                        #pragma unroll
                        for (int c = 0; c < 4; ++c)
                            #pragma unroll
                            for (int j = 0; j < 4; ++j)
                                gmax[c] = fmaxf(gmax[c], acc[c][j]);
                    } else {
                        #pragma unroll
                        for (int c = 0; c < 4; ++c)
                            #pragma unroll
                            for (int j = 0; j < 4; ++j) {
                                const int r = rt * 16 + lkg * 4 + j;
                                gmax[c] = fmaxf(gmax[c],
                                                (r < cnt) ? acc[c][j] : NEGF);
                            }
                    }
                }
                __syncthreads();   // reads done; safe to overwrite A
                if (vA) l1_write(pA0, pA1, pA2, wadr0);
                if (vB) l1_write(pB0, pB1, pB2, wadr0 + 4096u);
            }
        }

        // ---- din: wave-local columns (wave w owns cols w*64..+63) ----
        #pragma unroll
        for (int c = 0; c < 4; ++c) {
            float v = gmax[c];
            v = fmaxf(v, __shfl_xor(v, 16, 64));
            v = fmaxf(v, __shfl_xor(v, 32, 64));
            if (lane < 16) {
                const int col = wave * 64 + c * 16 + lane;
                const float biased = v + b2[col];
                const float actv = fmaxf(biased, 0.2f * biased);  // deferred leaky
                din[col] = (nrows > 0) ? actv : NEGF;             // empty-seg guard
            }
        }
        if (tid < 4) din[128 + tid] = conds[b * 4 + tid];
        __syncthreads();   // din complete

        // ---- decision net: one output column per thread, 4-way ILP ----
        float g0 = b3[tid], g1 = 0.f, g2 = 0.f, g3 = 0.f;
        #pragma unroll 4
        for (int i = 0; i < 132; i += 4) {
            g0 = fmaf(din[i + 0], w3[(i + 0) * 128 + tid], g0);
            g1 = fmaf(din[i + 1], w3[(i + 1) * 128 + tid], g1);
            g2 = fmaf(din[i + 2], w3[(i + 2) * 128 + tid], g2);
            g3 = fmaf(din[i + 3], w3[(i + 3) * 128 + tid], g3);
        }
        float g = (g0 + g1) + (g2 + g3);
        g = fmaxf(g, 0.2f * g);
        float part = g * w4[tid];
        #pragma unroll
        for (int s = 1; s < 64; s <<= 1)
            part += __shfl_xor(part, s, 64);
        if (lane == 0) red[wave] = part;
        __syncthreads();
        if (tid == 0) {
            float sc = (red[0] + red[1] + b4[0]) * scale;
            out[b] = fminf(fmaxf(sc, -1000.0f), 1000.0f);
        }
    }
}

extern "C" void kernel_launch(void* const* d_in, const int* in_sizes, int n_in,
                              void* d_out, int out_size, void* d_ws, size_t ws_size,
                              hipStream_t stream) {
    const float* muons = (const float*)d_in[0];
    const int*   bidx  = (const int*)d_in[1];
    const float* conds = (const float*)d_in[2];
    // d_in[3] = batch_size scalar (derive B from conditions instead)
    const float* w1 = (const float*)d_in[4];
    const float* b1 = (const float*)d_in[5];
    const float* w2 = (const float*)d_in[6];
    const float* b2 = (const float*)d_in[7];
    const float* w3 = (const float*)d_in[8];
    const float* b3 = (const float*)d_in[9];
    const float* w4 = (const float*)d_in[10];
    const float* b4 = (const float*)d_in[11];

    const int M = in_sizes[0] / 3;
    const int B = in_sizes[2] / 4;
    int* seg = (int*)d_ws;                                   // (B+1) ints
    const size_t off = (((size_t)(B + 1)) * 4 + 255) & ~(size_t)255;
    unsigned short* w2frag = (unsigned short*)((char*)d_ws + off);  // 32 KB
    const float scale = 1.0f / fmaxf(1.0f, sqrtf((float)B));

    seg_bounds_kernel<<<(M + 255) / 256, 256, 0, stream>>>(bidx, M, B, seg);
    prep_w2_kernel<<<32, 256, 0, stream>>>(w2, w2frag);
    const int nblk = (B + NB - 1) / NB;
    critic_kernel<<<nblk, 128, 0, stream>>>(muons, conds, seg,
                                            w1, b1, w2frag, b2, w3, b3, w4, b4,
                                            (float*)d_out, scale, B);
}